// Round 1
// baseline (2244.878 us; speedup 1.0000x reference)
//
#include <hip/hip_runtime.h>

// GCN 3-layer forward for MI355X (gfx950).
// Layers: h1 = relu(gcn(x, W1, b1)); h2 = relu(gcn(h1, W2, b2)); out = gcn(h2, W3, b3)
// gcn(x) = scatter_add(norm .* (xW)[src] -> dst) + selfloop(xW * dinv^2) + b
//
// Fusions:
//  - self-loop init (agg = h * dinv^2) fused into GEMM epilogue
//  - bias+ReLU of layer L fused into the A-tile load of GEMM L+1
// Workspace: dinv[N] | norm[E] | H[N*64] | AGGa[N*64] | AGGb[N*64]  (~81 MB)

#define NNODES 100000
#define NEDGES 1000000
#define INF 512

__global__ void k_init_deg(float* __restrict__ deg, int n) {
  int i = blockIdx.x * blockDim.x + threadIdx.x;
  if (i < n) deg[i] = 1.0f;  // self-loop weight
}

__global__ void k_deg_edges(const int* __restrict__ dst, const float* __restrict__ ew,
                            float* __restrict__ deg, int E) {
  int e = blockIdx.x * blockDim.x + threadIdx.x;
  if (e < E) atomicAdd(&deg[dst[e]], ew[e]);
}

__global__ void k_dinv(float* __restrict__ deg, int n) {
  int i = blockIdx.x * blockDim.x + threadIdx.x;
  if (i < n) {
    float d = deg[i];
    deg[i] = d > 0.f ? 1.0f / sqrtf(d) : 0.f;
  }
}

__global__ void k_norm(const int* __restrict__ src, const int* __restrict__ dst,
                       const float* __restrict__ ew, const float* __restrict__ dinv,
                       float* __restrict__ norm, int E) {
  int e = blockIdx.x * blockDim.x + threadIdx.x;
  if (e < E) norm[e] = dinv[src[e]] * ew[e] * dinv[dst[e]];
}

// C[M,64] = A[M,K] @ B[K,64]; also agg[row] = C[row] * dinv[row]^2.
// If FUSE_IN: A-element -> relu(A + bin[k]) (bias+ReLU of previous layer).
// 64x64 block tile, 16-deep K tiles, 256 threads, 4x4 microtile.
template <bool FUSE_IN>
__global__ __launch_bounds__(256) void k_gemm_n64(
    const float* __restrict__ A, const float* __restrict__ B,
    const float* __restrict__ bin, const float* __restrict__ dinv,
    float* __restrict__ C, float* __restrict__ agg, int M, int K) {
  __shared__ float As[16][68];  // [k][row], padded
  __shared__ float Bs[16][64];  // [k][col]
  const int tid = threadIdx.x;
  const int bm = blockIdx.x * 64;
  const int tx = tid & 15;   // col group
  const int ty = tid >> 4;   // row group (0..15)
  const int arow = tid >> 2;         // 0..63 (A-load row)
  const int akk = (tid & 3) << 2;    // 0,4,8,12 (A-load k offset)
  const int grow = bm + arow;
  const bool rowok = grow < M;

  float acc[4][4] = {};

  for (int k0 = 0; k0 < K; k0 += 16) {
    float4 a4 = make_float4(0.f, 0.f, 0.f, 0.f);
    if (rowok) {
      a4 = *(const float4*)(A + (size_t)grow * K + k0 + akk);
      if (FUSE_IN) {
        const float4 b4 = *(const float4*)(bin + k0 + akk);
        a4.x = fmaxf(a4.x + b4.x, 0.f);
        a4.y = fmaxf(a4.y + b4.y, 0.f);
        a4.z = fmaxf(a4.z + b4.z, 0.f);
        a4.w = fmaxf(a4.w + b4.w, 0.f);
      }
    }
    As[akk + 0][arow] = a4.x;
    As[akk + 1][arow] = a4.y;
    As[akk + 2][arow] = a4.z;
    As[akk + 3][arow] = a4.w;
    *(float4*)&Bs[ty][tx << 2] =
        *(const float4*)(B + (size_t)(k0 + ty) * 64 + (tx << 2));
    __syncthreads();
#pragma unroll
    for (int k = 0; k < 16; ++k) {
      const float4 av = *(const float4*)&As[k][ty << 2];
      const float4 bv = *(const float4*)&Bs[k][tx << 2];
      const float a_[4] = {av.x, av.y, av.z, av.w};
      const float b_[4] = {bv.x, bv.y, bv.z, bv.w};
#pragma unroll
      for (int i = 0; i < 4; ++i)
#pragma unroll
        for (int j = 0; j < 4; ++j)
          acc[i][j] = fmaf(a_[i], b_[j], acc[i][j]);
    }
    __syncthreads();
  }

  const int r0 = bm + (ty << 2);
  const int c0 = tx << 2;
#pragma unroll
  for (int r = 0; r < 4; ++r) {
    const int row = r0 + r;
    if (row < M) {
      const float4 v = make_float4(acc[r][0], acc[r][1], acc[r][2], acc[r][3]);
      *(float4*)(C + (size_t)row * 64 + c0) = v;
      const float di = dinv[row];
      const float w = di * di;
      *(float4*)(agg + (size_t)row * 64 + c0) =
          make_float4(v.x * w, v.y * w, v.z * w, v.w * w);
    }
  }
}

// C[M,16] = A[M,64] @ B[64,16]; agg = C * dinv^2; FUSE_IN as above.
template <bool FUSE_IN>
__global__ __launch_bounds__(256) void k_gemm_n16(
    const float* __restrict__ A, const float* __restrict__ B,
    const float* __restrict__ bin, const float* __restrict__ dinv,
    float* __restrict__ C, float* __restrict__ agg, int M) {
  __shared__ float Bs[64][16];
  const int tid = threadIdx.x;
  *(float4*)&((float*)Bs)[tid << 2] = *(const float4*)(B + (tid << 2));
  __syncthreads();
  const int col = tid & 15;
  const int rg = tid >> 4;  // 0..15
  const int row0 = blockIdx.x * 64 + (rg << 2);
  float acc[4] = {0.f, 0.f, 0.f, 0.f};
#pragma unroll 4
  for (int k0 = 0; k0 < 64; k0 += 4) {
    const float bv0 = Bs[k0 + 0][col];
    const float bv1 = Bs[k0 + 1][col];
    const float bv2 = Bs[k0 + 2][col];
    const float bv3 = Bs[k0 + 3][col];
    float4 bb;
    if (FUSE_IN) bb = *(const float4*)(bin + k0);
#pragma unroll
    for (int r = 0; r < 4; ++r) {
      const int row = row0 + r;
      if (row < M) {
        float4 a4 = *(const float4*)(A + (size_t)row * 64 + k0);
        if (FUSE_IN) {
          a4.x = fmaxf(a4.x + bb.x, 0.f);
          a4.y = fmaxf(a4.y + bb.y, 0.f);
          a4.z = fmaxf(a4.z + bb.z, 0.f);
          a4.w = fmaxf(a4.w + bb.w, 0.f);
        }
        acc[r] += a4.x * bv0 + a4.y * bv1 + a4.z * bv2 + a4.w * bv3;
      }
    }
  }
#pragma unroll
  for (int r = 0; r < 4; ++r) {
    const int row = row0 + r;
    if (row < M) {
      C[(size_t)row * 16 + col] = acc[r];
      const float di = dinv[row];
      agg[(size_t)row * 16 + col] = acc[r] * di * di;
    }
  }
}

// agg[dst] += H[src] * norm, NF features per edge, 4 floats per thread.
template <int NF>
__global__ void k_scatter(const float* __restrict__ H, const float* __restrict__ norm,
                          const int* __restrict__ src, const int* __restrict__ dst,
                          float* __restrict__ agg, int E) {
  const int TPE = NF / 4;
  const long long t = (long long)blockIdx.x * blockDim.x + threadIdx.x;
  if (t >= (long long)E * TPE) return;
  const int e = (int)(t / TPE);
  const int fo = ((int)(t % TPE)) << 2;
  const int s = src[e];
  const int d = dst[e];
  const float w = norm[e];
  const float4 h4 = *(const float4*)(H + (size_t)s * NF + fo);
  float* out = agg + (size_t)d * NF + fo;
  atomicAdd(out + 0, h4.x * w);
  atomicAdd(out + 1, h4.y * w);
  atomicAdd(out + 2, h4.z * w);
  atomicAdd(out + 3, h4.w * w);
}

__global__ void k_finalize16(const float* __restrict__ agg, const float* __restrict__ b,
                             float* __restrict__ out, int N) {
  const int t = blockIdx.x * blockDim.x + threadIdx.x;
  if (t >= N * 4) return;
  const int i = t >> 2;
  const int fo = (t & 3) << 2;
  const float4 v = *(const float4*)(agg + (size_t)i * 16 + fo);
  const float4 bb = *(const float4*)(b + fo);
  *(float4*)(out + (size_t)i * 16 + fo) =
      make_float4(v.x + bb.x, v.y + bb.y, v.z + bb.z, v.w + bb.w);
}

extern "C" void kernel_launch(void* const* d_in, const int* in_sizes, int n_in,
                              void* d_out, int out_size, void* d_ws, size_t ws_size,
                              hipStream_t stream) {
  const float* features = (const float*)d_in[0];
  const int* edge_index = (const int*)d_in[1];
  const float* ew = (const float*)d_in[2];
  const float* W1 = (const float*)d_in[3];
  const float* b1 = (const float*)d_in[4];
  const float* W2 = (const float*)d_in[5];
  const float* b2 = (const float*)d_in[6];
  const float* W3 = (const float*)d_in[7];
  const float* b3 = (const float*)d_in[8];

  const int N = NNODES;
  const int E = NEDGES;
  const int* src = edge_index;
  const int* dst = edge_index + E;

  float* ws = (float*)d_ws;
  float* dinv = ws;                       // N
  float* norm = dinv + N;                 // E
  float* H    = norm + E;                 // N*64
  float* AGGa = H + (size_t)N * 64;       // N*64
  float* AGGb = AGGa + (size_t)N * 64;    // N*64

  const int B = 256;
  const int gN = (N + B - 1) / B;
  const int gE = (E + B - 1) / B;
  const int gblk = (N + 63) / 64;

  // degree + norm precompute (deg computed in-place in dinv buffer)
  k_init_deg<<<gN, B, 0, stream>>>(dinv, N);
  k_deg_edges<<<gE, B, 0, stream>>>(dst, ew, dinv, E);
  k_dinv<<<gN, B, 0, stream>>>(dinv, N);
  k_norm<<<gE, B, 0, stream>>>(src, dst, ew, dinv, norm, E);

  const int gS64 = (int)(((long long)E * 16 + B - 1) / B);
  const int gS16 = (int)(((long long)E * 4 + B - 1) / B);

  // layer 1: H = X@W1 ; AGGa = selfloop + scatter
  k_gemm_n64<false><<<gblk, 256, 0, stream>>>(features, W1, nullptr, dinv, H, AGGa, N, INF);
  k_scatter<64><<<gS64, B, 0, stream>>>(H, norm, src, dst, AGGa, E);

  // layer 2: A = relu(AGGa + b1) fused; H = A@W2 ; AGGb
  k_gemm_n64<true><<<gblk, 256, 0, stream>>>(AGGa, W2, b1, dinv, H, AGGb, N, 64);
  k_scatter<64><<<gS64, B, 0, stream>>>(H, norm, src, dst, AGGb, E);

  // layer 3: A = relu(AGGb + b2) fused; H16 = A@W3 ; AGGa (as N*16)
  k_gemm_n16<true><<<gblk, 256, 0, stream>>>(AGGb, W3, b2, dinv, H, AGGa, N);
  k_scatter<16><<<gS16, B, 0, stream>>>(H, norm, src, dst, AGGa, E);

  // out = AGGa + b3
  k_finalize16<<<(N * 4 + B - 1) / B, B, 0, stream>>>(AGGa, b3, (float*)d_out, N);
}

// Round 8
// 681.001 us; speedup vs baseline: 3.2964x; 3.2964x over previous
//
#include <hip/hip_runtime.h>

// GCN 3-layer forward for MI355X (gfx950) — R2b: CSR gather instead of atomic scatter.
// gcn(x) = gather_csr(norm .* (xW)[src]) + selfloop(xW * dinv^2) + b
//
// R2b: workspace reordered so ep (int2) / H / AGG (float4) are 16B-aligned.
// Pipeline per call (workspace is re-poisoned every call, so CSR is rebuilt):
//  init(deg=1,cnt=0) -> deg/cnt atomics -> dinv -> scan(cnt)->rs -> fill(ep)
//  GEMM1(X,W1)->H ; gather64(H)->AGG
//  GEMM2(AGG+b1,relu,W2)->H ; gather64(H)->AGG
//  GEMM3(AGG+b2,relu,W3)->H16 ; gather16(H16)+b3 -> out

#define NNODES 100000
#define NEDGES 1000000
#define INF 512
#define SCAN_B 512

__global__ void k_init(float* __restrict__ deg, int* __restrict__ cnt, int n) {
  int i = blockIdx.x * blockDim.x + threadIdx.x;
  if (i < n) { deg[i] = 1.0f; cnt[i] = 0; }
}

__global__ void k_deg_cnt(const int* __restrict__ dst, const float* __restrict__ ew,
                          float* __restrict__ deg, int* __restrict__ cnt, int E) {
  int e = blockIdx.x * blockDim.x + threadIdx.x;
  if (e < E) {
    int d = dst[e];
    atomicAdd(&deg[d], ew[e]);
    atomicAdd(&cnt[d], 1);
  }
}

__global__ void k_dinv(float* __restrict__ deg, int n) {
  int i = blockIdx.x * blockDim.x + threadIdx.x;
  if (i < n) {
    float d = deg[i];
    deg[i] = d > 0.f ? 1.0f / sqrtf(d) : 0.f;
  }
}

// exclusive scan, stage 1: per-block (512) Hillis-Steele
__global__ __launch_bounds__(SCAN_B) void k_scan1(const int* __restrict__ cnt,
                                                  int* __restrict__ rs,
                                                  int* __restrict__ bsums, int n) {
  __shared__ int s[SCAN_B];
  const int t = threadIdx.x;
  const int i = blockIdx.x * SCAN_B + t;
  int v = (i < n) ? cnt[i] : 0;
  s[t] = v;
  __syncthreads();
  int acc = v;
#pragma unroll
  for (int off = 1; off < SCAN_B; off <<= 1) {
    int add = (t >= off) ? s[t - off] : 0;
    __syncthreads();
    acc += add;
    s[t] = acc;
    __syncthreads();
  }
  if (i < n) rs[i] = acc - v;              // exclusive
  if (t == SCAN_B - 1) bsums[blockIdx.x] = acc;  // block total
}

// stage 2: scan the block sums (nb <= 256), in-place exclusive
__global__ __launch_bounds__(256) void k_scan2(int* __restrict__ bsums, int nb) {
  __shared__ int s[256];
  const int t = threadIdx.x;
  int v = (t < nb) ? bsums[t] : 0;
  s[t] = v;
  __syncthreads();
  int acc = v;
#pragma unroll
  for (int off = 1; off < 256; off <<= 1) {
    int add = (t >= off) ? s[t - off] : 0;
    __syncthreads();
    acc += add;
    s[t] = acc;
    __syncthreads();
  }
  if (t < nb) bsums[t] = acc - v;
}

// stage 3: add block offsets; zero cnt (it becomes the fill cursor); rs[n]=E
__global__ void k_scan3(int* __restrict__ rs, const int* __restrict__ bsums,
                        int* __restrict__ cnt, int n, int E) {
  int i = blockIdx.x * blockDim.x + threadIdx.x;
  if (i < n) {
    rs[i] += bsums[i / SCAN_B];
    cnt[i] = 0;
  }
  if (i == 0) rs[n] = E;
}

// fill CSR: ep[pos] = {src, norm}; norm computed inline
__global__ void k_fill(const int* __restrict__ src, const int* __restrict__ dst,
                       const float* __restrict__ ew, const float* __restrict__ dinv,
                       const int* __restrict__ rs, int* __restrict__ cur,
                       int2* __restrict__ ep, int E) {
  int e = blockIdx.x * blockDim.x + threadIdx.x;
  if (e < E) {
    const int s = src[e], d = dst[e];
    const int pos = rs[d] + atomicAdd(&cur[d], 1);
    const float nm = dinv[s] * ew[e] * dinv[d];
    ep[pos] = make_int2(s, __float_as_int(nm));
  }
}

// C[M,64] = A[M,K] @ B[K,64]. If FUSE_IN: A -> relu(A + bin[k]).
template <bool FUSE_IN>
__global__ __launch_bounds__(256) void k_gemm_n64(
    const float* __restrict__ A, const float* __restrict__ B,
    const float* __restrict__ bin, float* __restrict__ C, int M, int K) {
  __shared__ float As[16][68];  // [k][row], padded
  __shared__ float Bs[16][64];  // [k][col]
  const int tid = threadIdx.x;
  const int bm = blockIdx.x * 64;
  const int tx = tid & 15;
  const int ty = tid >> 4;
  const int arow = tid >> 2;
  const int akk = (tid & 3) << 2;
  const int grow = bm + arow;
  const bool rowok = grow < M;

  float acc[4][4] = {};

  for (int k0 = 0; k0 < K; k0 += 16) {
    float4 a4 = make_float4(0.f, 0.f, 0.f, 0.f);
    if (rowok) {
      a4 = *(const float4*)(A + (size_t)grow * K + k0 + akk);
      if (FUSE_IN) {
        const float4 b4 = *(const float4*)(bin + k0 + akk);
        a4.x = fmaxf(a4.x + b4.x, 0.f);
        a4.y = fmaxf(a4.y + b4.y, 0.f);
        a4.z = fmaxf(a4.z + b4.z, 0.f);
        a4.w = fmaxf(a4.w + b4.w, 0.f);
      }
    }
    As[akk + 0][arow] = a4.x;
    As[akk + 1][arow] = a4.y;
    As[akk + 2][arow] = a4.z;
    As[akk + 3][arow] = a4.w;
    *(float4*)&Bs[ty][tx << 2] =
        *(const float4*)(B + (size_t)(k0 + ty) * 64 + (tx << 2));
    __syncthreads();
#pragma unroll
    for (int k = 0; k < 16; ++k) {
      const float4 av = *(const float4*)&As[k][ty << 2];
      const float4 bv = *(const float4*)&Bs[k][tx << 2];
      const float a_[4] = {av.x, av.y, av.z, av.w};
      const float b_[4] = {bv.x, bv.y, bv.z, bv.w};
#pragma unroll
      for (int i = 0; i < 4; ++i)
#pragma unroll
        for (int j = 0; j < 4; ++j)
          acc[i][j] = fmaf(a_[i], b_[j], acc[i][j]);
    }
    __syncthreads();
  }

  const int r0 = bm + (ty << 2);
  const int c0 = tx << 2;
#pragma unroll
  for (int r = 0; r < 4; ++r) {
    const int row = r0 + r;
    if (row < M)
      *(float4*)(C + (size_t)row * 64 + c0) =
          make_float4(acc[r][0], acc[r][1], acc[r][2], acc[r][3]);
  }
}

// C[M,16] = A[M,64] @ B[64,16]; FUSE_IN as above.
template <bool FUSE_IN>
__global__ __launch_bounds__(256) void k_gemm_n16(
    const float* __restrict__ A, const float* __restrict__ B,
    const float* __restrict__ bin, float* __restrict__ C, int M) {
  __shared__ float Bs[64][16];
  const int tid = threadIdx.x;
  *(float4*)&((float*)Bs)[tid << 2] = *(const float4*)(B + (tid << 2));
  __syncthreads();
  const int col = tid & 15;
  const int rg = tid >> 4;
  const int row0 = blockIdx.x * 64 + (rg << 2);
  float acc[4] = {0.f, 0.f, 0.f, 0.f};
#pragma unroll 4
  for (int k0 = 0; k0 < 64; k0 += 4) {
    const float bv0 = Bs[k0 + 0][col];
    const float bv1 = Bs[k0 + 1][col];
    const float bv2 = Bs[k0 + 2][col];
    const float bv3 = Bs[k0 + 3][col];
    float4 bb;
    if (FUSE_IN) bb = *(const float4*)(bin + k0);
#pragma unroll
    for (int r = 0; r < 4; ++r) {
      const int row = row0 + r;
      if (row < M) {
        float4 a4 = *(const float4*)(A + (size_t)row * 64 + k0);
        if (FUSE_IN) {
          a4.x = fmaxf(a4.x + bb.x, 0.f);
          a4.y = fmaxf(a4.y + bb.y, 0.f);
          a4.z = fmaxf(a4.z + bb.z, 0.f);
          a4.w = fmaxf(a4.w + bb.w, 0.f);
        }
        acc[r] += a4.x * bv0 + a4.y * bv1 + a4.z * bv2 + a4.w * bv3;
      }
    }
  }
#pragma unroll
  for (int r = 0; r < 4; ++r) {
    const int row = row0 + r;
    if (row < M) C[(size_t)row * 16 + col] = acc[r];
  }
}

// one wave per node, lane = feature; agg = selfloop + sum_{in-edges} H[src]*norm
__global__ __launch_bounds__(256) void k_gather64(
    const float* __restrict__ H, const int2* __restrict__ ep,
    const int* __restrict__ rs, const float* __restrict__ dinv,
    float* __restrict__ agg, int N) {
  const int w = (blockIdx.x * 256 + threadIdx.x) >> 6;
  const int lane = threadIdx.x & 63;
  if (w >= N) return;
  const int s0 = rs[w], s1 = rs[w + 1];
  const float di = dinv[w];
  float acc = H[(size_t)w * 64 + lane] * di * di;
  int j = s0;
  for (; j + 1 < s1; j += 2) {
    const int2 pa = ep[j];
    const int2 pb = ep[j + 1];
    const float ha = H[(size_t)pa.x * 64 + lane];
    const float hb = H[(size_t)pb.x * 64 + lane];
    acc = fmaf(ha, __int_as_float(pa.y), acc);
    acc = fmaf(hb, __int_as_float(pb.y), acc);
  }
  if (j < s1) {
    const int2 p = ep[j];
    acc = fmaf(H[(size_t)p.x * 64 + lane], __int_as_float(p.y), acc);
  }
  agg[(size_t)w * 64 + lane] = acc;
}

// thread per (node, feature), 16 features; writes out = agg + b directly
__global__ __launch_bounds__(256) void k_gather16(
    const float* __restrict__ H, const int2* __restrict__ ep,
    const int* __restrict__ rs, const float* __restrict__ dinv,
    const float* __restrict__ b, float* __restrict__ out, int N) {
  const int t = blockIdx.x * blockDim.x + threadIdx.x;
  if (t >= N * 16) return;
  const int n = t >> 4;
  const int f = t & 15;
  const int s0 = rs[n], s1 = rs[n + 1];
  const float di = dinv[n];
  float acc = H[(size_t)n * 16 + f] * di * di;
  for (int j = s0; j < s1; ++j) {
    const int2 p = ep[j];
    acc = fmaf(H[(size_t)p.x * 16 + f], __int_as_float(p.y), acc);
  }
  out[(size_t)n * 16 + f] = acc + b[f];
}

extern "C" void kernel_launch(void* const* d_in, const int* in_sizes, int n_in,
                              void* d_out, int out_size, void* d_ws, size_t ws_size,
                              hipStream_t stream) {
  const float* features = (const float*)d_in[0];
  const int* edge_index = (const int*)d_in[1];
  const float* ew = (const float*)d_in[2];
  const float* W1 = (const float*)d_in[3];
  const float* b1 = (const float*)d_in[4];
  const float* W2 = (const float*)d_in[5];
  const float* b2 = (const float*)d_in[6];
  const float* W3 = (const float*)d_in[7];
  const float* b3 = (const float*)d_in[8];

  const int N = NNODES;
  const int E = NEDGES;
  const int* src = edge_index;
  const int* dst = edge_index + E;

  // workspace layout (wide-access buffers first for 16B alignment):
  //   ep 2E ints | H N*64 f | AGG N*64 f | dinv N | cnt N | rs N+1 | bsums 256
  int2* ep = (int2*)d_ws;                       // 8,000,000 B (16B-aligned)
  float* H = (float*)(ep + E);                  // 25,600,000 B (16B-aligned)
  float* AGG = H + (size_t)N * 64;              // 25,600,000 B (16B-aligned)
  float* dinv = AGG + (size_t)N * 64;
  int* cnt = (int*)(dinv + N);
  int* rs = cnt + N;
  int* bsums = rs + N + 1;

  const int B = 256;
  const int gN = (N + B - 1) / B;
  const int gE = (E + B - 1) / B;
  const int gblk = (N + 63) / 64;
  const int nb1 = (N + SCAN_B - 1) / SCAN_B;  // 196

  // CSR build + norms
  k_init<<<gN, B, 0, stream>>>(dinv, cnt, N);
  k_deg_cnt<<<gE, B, 0, stream>>>(dst, ew, dinv, cnt, E);
  k_dinv<<<gN, B, 0, stream>>>(dinv, N);
  k_scan1<<<nb1, SCAN_B, 0, stream>>>(cnt, rs, bsums, N);
  k_scan2<<<1, 256, 0, stream>>>(bsums, nb1);
  k_scan3<<<gN, B, 0, stream>>>(rs, bsums, cnt, N, E);
  k_fill<<<gE, B, 0, stream>>>(src, dst, ew, dinv, rs, cnt, ep, E);

  // layer 1
  k_gemm_n64<false><<<gblk, 256, 0, stream>>>(features, W1, nullptr, H, N, INF);
  k_gather64<<<(N * 64 + 255) / 256, 256, 0, stream>>>(H, ep, rs, dinv, AGG, N);

  // layer 2 (bias+relu of layer 1 fused into A-load)
  k_gemm_n64<true><<<gblk, 256, 0, stream>>>(AGG, W2, b1, H, N, 64);
  k_gather64<<<(N * 64 + 255) / 256, 256, 0, stream>>>(H, ep, rs, dinv, AGG, N);

  // layer 3 (bias+relu fused), 16-wide; H reused for the N x 16 result
  k_gemm_n16<true><<<gblk, 256, 0, stream>>>(AGG, W3, b2, H, N);
  k_gather16<<<(N * 16 + 255) / 256, 256, 0, stream>>>(H, ep, rs, dinv, b3, (float*)d_out, N);
}

// Round 9
// 637.954 us; speedup vs baseline: 3.5189x; 1.0675x over previous
//
#include <hip/hip_runtime.h>

// GCN 3-layer forward, MI355X (gfx950) — R9: bf16x3-split MFMA for GEMM1.
// gcn(x) = gather_csr(norm .* (xW)[src]) + selfloop(xW * dinv^2) + b
// R9 changes vs R8 (681 us):
//  - GEMM1 (100k x 512 @ 512 x 64) now uses mfma_f32_16x16x32_bf16 with
//    3-product bf16 split (hi*hi + lo*hi + hi*lo) ~= fp32 accuracy.
//  - k_dinv folded into k_scan1 (saves a dispatch + a pass over deg).
//  - gather64 unrolled 4-deep for memory-level parallelism.

#define NNODES 100000
#define NEDGES 1000000
#define INF 512
#define SCAN_B 512

typedef float f32x4_t __attribute__((ext_vector_type(4)));
typedef short s16x8_t __attribute__((ext_vector_type(8)));

__device__ __forceinline__ unsigned short f2bf(float x) {
  unsigned u = __float_as_uint(x);
  return (unsigned short)((u + 0x7FFFu + ((u >> 16) & 1u)) >> 16);
}
__device__ __forceinline__ float bf2f(unsigned short h) {
  return __uint_as_float(((unsigned)h) << 16);
}

__global__ void k_init(float* __restrict__ deg, int* __restrict__ cnt, int n) {
  int i = blockIdx.x * blockDim.x + threadIdx.x;
  if (i < n) { deg[i] = 1.0f; cnt[i] = 0; }
}

__global__ void k_deg_cnt(const int* __restrict__ dst, const float* __restrict__ ew,
                          float* __restrict__ deg, int* __restrict__ cnt, int E) {
  int e = blockIdx.x * blockDim.x + threadIdx.x;
  if (e < E) {
    int d = dst[e];
    atomicAdd(&deg[d], ew[e]);
    atomicAdd(&cnt[d], 1);
  }
}

// exclusive scan stage 1 (per-block Hillis-Steele) + fused dinv: deg -> 1/sqrt(deg)
__global__ __launch_bounds__(SCAN_B) void k_scan1(const int* __restrict__ cnt,
                                                  int* __restrict__ rs,
                                                  int* __restrict__ bsums,
                                                  float* __restrict__ deg, int n) {
  __shared__ int s[SCAN_B];
  const int t = threadIdx.x;
  const int i = blockIdx.x * SCAN_B + t;
  int v = (i < n) ? cnt[i] : 0;
  s[t] = v;
  __syncthreads();
  int acc = v;
#pragma unroll
  for (int off = 1; off < SCAN_B; off <<= 1) {
    int add = (t >= off) ? s[t - off] : 0;
    __syncthreads();
    acc += add;
    s[t] = acc;
    __syncthreads();
  }
  if (i < n) {
    rs[i] = acc - v;  // exclusive
    float d = deg[i];
    deg[i] = d > 0.f ? 1.0f / sqrtf(d) : 0.f;  // fused k_dinv
  }
  if (t == SCAN_B - 1) bsums[blockIdx.x] = acc;
}

__global__ __launch_bounds__(256) void k_scan2(int* __restrict__ bsums, int nb) {
  __shared__ int s[256];
  const int t = threadIdx.x;
  int v = (t < nb) ? bsums[t] : 0;
  s[t] = v;
  __syncthreads();
  int acc = v;
#pragma unroll
  for (int off = 1; off < 256; off <<= 1) {
    int add = (t >= off) ? s[t - off] : 0;
    __syncthreads();
    acc += add;
    s[t] = acc;
    __syncthreads();
  }
  if (t < nb) bsums[t] = acc - v;
}

__global__ void k_scan3(int* __restrict__ rs, const int* __restrict__ bsums,
                        int* __restrict__ cnt, int n, int E) {
  int i = blockIdx.x * blockDim.x + threadIdx.x;
  if (i < n) {
    rs[i] += bsums[i / SCAN_B];
    cnt[i] = 0;
  }
  if (i == 0) rs[n] = E;
}

__global__ void k_fill(const int* __restrict__ src, const int* __restrict__ dst,
                       const float* __restrict__ ew, const float* __restrict__ dinv,
                       const int* __restrict__ rs, int* __restrict__ cur,
                       int2* __restrict__ ep, int E) {
  int e = blockIdx.x * blockDim.x + threadIdx.x;
  if (e < E) {
    const int s = src[e], d = dst[e];
    const int pos = rs[d] + atomicAdd(&cur[d], 1);
    const float nm = dinv[s] * ew[e] * dinv[d];
    ep[pos] = make_int2(s, __float_as_int(nm));
  }
}

// ---------------- GEMM1: H[M,64] = A[M,512] @ W[512,64], bf16x3 MFMA ----------------
// 256 threads (4 waves). Block tile 128x64, K-step 32. Wave w owns rows w*32..w*32+31
// (2 row-tiles of 16). MFMA 16x16x32_bf16; C/D: col=lane&15, row=(lane>>4)*4+j (m89).
// A staged fp32 in LDS [128][36] (pad -> 2-way bank conflicts only);
// W staged pre-swizzled per-lane bf16 hi/lo fragments (ds_read_b128 per frag).
__global__ __launch_bounds__(256) void k_gemm1_mfma(
    const float* __restrict__ A, const float* __restrict__ W,
    float* __restrict__ C, int M) {
  __shared__ float As[128][36];
  __shared__ short Bhi[4][64][8];
  __shared__ short Blo[4][64][8];

  const int tid = threadIdx.x;
  const int bm = blockIdx.x * 128;
  const int wv = tid >> 6;       // wave 0..3
  const int l = tid & 63;        // lane
  const int m0 = l & 15;         // row-in-tile / col-in-tile
  const int kg = l >> 4;         // k-group 0..3 (k = kg*8 + i)

  f32x4_t acc[2][4];
#pragma unroll
  for (int r = 0; r < 2; ++r)
#pragma unroll
    for (int c = 0; c < 4; ++c) acc[r][c] = (f32x4_t)0.f;

  // B staging coords (whole W column-fragment per thread per K-step)
  const int bc = tid >> 6;          // coltile 0..3
  const int bcol = bc * 16 + m0;    // 0..63

  for (int k0 = 0; k0 < INF; k0 += 32) {
    // --- stage A tile [128][32] fp32, coalesced float4 ---
#pragma unroll
    for (int i = 0; i < 4; ++i) {
      const int idx = i * 256 + tid;      // 0..1023
      const int row = idx >> 3;           // 0..127
      const int kq = (idx & 7) << 2;      // 0,4,..,28
      const int grow = bm + row;
      float4 v = make_float4(0.f, 0.f, 0.f, 0.f);
      if (grow < M) v = *(const float4*)(A + (size_t)grow * INF + k0 + kq);
      *(float4*)&As[row][kq] = v;
    }
    // --- stage W fragment (bf16 hi/lo, pre-swizzled to lane order) ---
    {
      s16x8_t bh, bl;
#pragma unroll
      for (int i = 0; i < 8; ++i) {
        const float w = W[(size_t)(k0 + kg * 8 + i) * 64 + bcol];
        const unsigned short h = f2bf(w);
        bh[i] = (short)h;
        bl[i] = (short)f2bf(w - bf2f(h));
      }
      *(s16x8_t*)&Bhi[bc][l][0] = bh;
      *(s16x8_t*)&Blo[bc][l][0] = bl;
    }
    __syncthreads();

    // --- A fragments (fp32 -> bf16 hi/lo) ---
    s16x8_t ahi[2], alo[2];
#pragma unroll
    for (int r = 0; r < 2; ++r) {
      const float* ap = &As[wv * 32 + r * 16 + m0][kg * 8];
      const float4 x0 = *(const float4*)ap;
      const float4 x1 = *(const float4*)(ap + 4);
      const float xs[8] = {x0.x, x0.y, x0.z, x0.w, x1.x, x1.y, x1.z, x1.w};
#pragma unroll
      for (int i = 0; i < 8; ++i) {
        const unsigned short h = f2bf(xs[i]);
        ahi[r][i] = (short)h;
        alo[r][i] = (short)f2bf(xs[i] - bf2f(h));
      }
    }
    // --- MFMA: hi*hi + lo*hi + hi*lo ---
#pragma unroll
    for (int c = 0; c < 4; ++c) {
      const s16x8_t bh = *(const s16x8_t*)&Bhi[c][l][0];
      const s16x8_t bl = *(const s16x8_t*)&Blo[c][l][0];
#pragma unroll
      for (int r = 0; r < 2; ++r) {
        acc[r][c] = __builtin_amdgcn_mfma_f32_16x16x32_bf16(ahi[r], bh, acc[r][c], 0, 0, 0);
        acc[r][c] = __builtin_amdgcn_mfma_f32_16x16x32_bf16(alo[r], bh, acc[r][c], 0, 0, 0);
        acc[r][c] = __builtin_amdgcn_mfma_f32_16x16x32_bf16(ahi[r], bl, acc[r][c], 0, 0, 0);
      }
    }
    __syncthreads();
  }

  // --- C write: row=(l>>4)*4+j within tile, col=l&15 ---
#pragma unroll
  for (int r = 0; r < 2; ++r) {
    const int rowbase = bm + wv * 32 + r * 16 + (l >> 4) * 4;
#pragma unroll
    for (int j = 0; j < 4; ++j) {
      const int row = rowbase + j;
      if (row < M) {
#pragma unroll
        for (int c = 0; c < 4; ++c)
          C[(size_t)row * 64 + c * 16 + m0] = acc[r][c][j];
      }
    }
  }
}

// C[M,64] = A[M,64] @ B[64,64] with relu(A + bin) fused (layer 2). fp32 VALU.
__global__ __launch_bounds__(256) void k_gemm_n64(
    const float* __restrict__ A, const float* __restrict__ B,
    const float* __restrict__ bin, float* __restrict__ C, int M, int K) {
  __shared__ float As[16][68];
  __shared__ float Bs[16][64];
  const int tid = threadIdx.x;
  const int bm = blockIdx.x * 64;
  const int tx = tid & 15;
  const int ty = tid >> 4;
  const int arow = tid >> 2;
  const int akk = (tid & 3) << 2;
  const int grow = bm + arow;
  const bool rowok = grow < M;

  float acc[4][4] = {};

  for (int k0 = 0; k0 < K; k0 += 16) {
    float4 a4 = make_float4(0.f, 0.f, 0.f, 0.f);
    if (rowok) {
      a4 = *(const float4*)(A + (size_t)grow * K + k0 + akk);
      const float4 b4 = *(const float4*)(bin + k0 + akk);
      a4.x = fmaxf(a4.x + b4.x, 0.f);
      a4.y = fmaxf(a4.y + b4.y, 0.f);
      a4.z = fmaxf(a4.z + b4.z, 0.f);
      a4.w = fmaxf(a4.w + b4.w, 0.f);
    }
    As[akk + 0][arow] = a4.x;
    As[akk + 1][arow] = a4.y;
    As[akk + 2][arow] = a4.z;
    As[akk + 3][arow] = a4.w;
    *(float4*)&Bs[ty][tx << 2] =
        *(const float4*)(B + (size_t)(k0 + ty) * 64 + (tx << 2));
    __syncthreads();
#pragma unroll
    for (int k = 0; k < 16; ++k) {
      const float4 av = *(const float4*)&As[k][ty << 2];
      const float4 bv = *(const float4*)&Bs[k][tx << 2];
      const float a_[4] = {av.x, av.y, av.z, av.w};
      const float b_[4] = {bv.x, bv.y, bv.z, bv.w};
#pragma unroll
      for (int i = 0; i < 4; ++i)
#pragma unroll
        for (int j = 0; j < 4; ++j)
          acc[i][j] = fmaf(a_[i], b_[j], acc[i][j]);
    }
    __syncthreads();
  }

  const int r0 = bm + (ty << 2);
  const int c0 = tx << 2;
#pragma unroll
  for (int r = 0; r < 4; ++r) {
    const int row = r0 + r;
    if (row < M)
      *(float4*)(C + (size_t)row * 64 + c0) =
          make_float4(acc[r][0], acc[r][1], acc[r][2], acc[r][3]);
  }
}

// C[M,16] = relu(A+bin)[M,64] @ B[64,16] (layer 3). fp32 VALU.
__global__ __launch_bounds__(256) void k_gemm_n16(
    const float* __restrict__ A, const float* __restrict__ B,
    const float* __restrict__ bin, float* __restrict__ C, int M) {
  __shared__ float Bs[64][16];
  const int tid = threadIdx.x;
  *(float4*)&((float*)Bs)[tid << 2] = *(const float4*)(B + (tid << 2));
  __syncthreads();
  const int col = tid & 15;
  const int rg = tid >> 4;
  const int row0 = blockIdx.x * 64 + (rg << 2);
  float acc[4] = {0.f, 0.f, 0.f, 0.f};
#pragma unroll 4
  for (int k0 = 0; k0 < 64; k0 += 4) {
    const float bv0 = Bs[k0 + 0][col];
    const float bv1 = Bs[k0 + 1][col];
    const float bv2 = Bs[k0 + 2][col];
    const float bv3 = Bs[k0 + 3][col];
    const float4 bb = *(const float4*)(bin + k0);
#pragma unroll
    for (int r = 0; r < 4; ++r) {
      const int row = row0 + r;
      if (row < M) {
        float4 a4 = *(const float4*)(A + (size_t)row * 64 + k0);
        a4.x = fmaxf(a4.x + bb.x, 0.f);
        a4.y = fmaxf(a4.y + bb.y, 0.f);
        a4.z = fmaxf(a4.z + bb.z, 0.f);
        a4.w = fmaxf(a4.w + bb.w, 0.f);
        acc[r] += a4.x * bv0 + a4.y * bv1 + a4.z * bv2 + a4.w * bv3;
      }
    }
  }
#pragma unroll
  for (int r = 0; r < 4; ++r) {
    const int row = row0 + r;
    if (row < M) C[(size_t)row * 16 + col] = acc[r];
  }
}

// one wave per node, lane = feature; 4-deep unroll for MLP
__global__ __launch_bounds__(256) void k_gather64(
    const float* __restrict__ H, const int2* __restrict__ ep,
    const int* __restrict__ rs, const float* __restrict__ dinv,
    float* __restrict__ agg, int N) {
  const int w = (blockIdx.x * 256 + threadIdx.x) >> 6;
  const int lane = threadIdx.x & 63;
  if (w >= N) return;
  const int s0 = rs[w], s1 = rs[w + 1];
  const float di = dinv[w];
  float acc = H[(size_t)w * 64 + lane] * di * di;
  int j = s0;
  for (; j + 3 < s1; j += 4) {
    const int2 p0 = ep[j + 0];
    const int2 p1 = ep[j + 1];
    const int2 p2 = ep[j + 2];
    const int2 p3 = ep[j + 3];
    const float h0 = H[(size_t)p0.x * 64 + lane];
    const float h1 = H[(size_t)p1.x * 64 + lane];
    const float h2 = H[(size_t)p2.x * 64 + lane];
    const float h3 = H[(size_t)p3.x * 64 + lane];
    acc = fmaf(h0, __int_as_float(p0.y), acc);
    acc = fmaf(h1, __int_as_float(p1.y), acc);
    acc = fmaf(h2, __int_as_float(p2.y), acc);
    acc = fmaf(h3, __int_as_float(p3.y), acc);
  }
  for (; j < s1; ++j) {
    const int2 p = ep[j];
    acc = fmaf(H[(size_t)p.x * 64 + lane], __int_as_float(p.y), acc);
  }
  agg[(size_t)w * 64 + lane] = acc;
}

// thread per (node, feature); writes out = agg + b directly
__global__ __launch_bounds__(256) void k_gather16(
    const float* __restrict__ H, const int2* __restrict__ ep,
    const int* __restrict__ rs, const float* __restrict__ dinv,
    const float* __restrict__ b, float* __restrict__ out, int N) {
  const int t = blockIdx.x * blockDim.x + threadIdx.x;
  if (t >= N * 16) return;
  const int n = t >> 4;
  const int f = t & 15;
  const int s0 = rs[n], s1 = rs[n + 1];
  const float di = dinv[n];
  float acc = H[(size_t)n * 16 + f] * di * di;
  for (int j = s0; j < s1; ++j) {
    const int2 p = ep[j];
    acc = fmaf(H[(size_t)p.x * 16 + f], __int_as_float(p.y), acc);
  }
  out[(size_t)n * 16 + f] = acc + b[f];
}

extern "C" void kernel_launch(void* const* d_in, const int* in_sizes, int n_in,
                              void* d_out, int out_size, void* d_ws, size_t ws_size,
                              hipStream_t stream) {
  const float* features = (const float*)d_in[0];
  const int* edge_index = (const int*)d_in[1];
  const float* ew = (const float*)d_in[2];
  const float* W1 = (const float*)d_in[3];
  const float* b1 = (const float*)d_in[4];
  const float* W2 = (const float*)d_in[5];
  const float* b2 = (const float*)d_in[6];
  const float* W3 = (const float*)d_in[7];
  const float* b3 = (const float*)d_in[8];

  const int N = NNODES;
  const int E = NEDGES;
  const int* src = edge_index;
  const int* dst = edge_index + E;

  // workspace (wide-access buffers first for 16B alignment):
  //   ep 2E ints | H N*64 f | AGG N*64 f | dinv N | cnt N | rs N+1 | bsums 256
  int2* ep = (int2*)d_ws;
  float* H = (float*)(ep + E);
  float* AGG = H + (size_t)N * 64;
  float* dinv = AGG + (size_t)N * 64;
  int* cnt = (int*)(dinv + N);
  int* rs = cnt + N;
  int* bsums = rs + N + 1;

  const int B = 256;
  const int gN = (N + B - 1) / B;
  const int gE = (E + B - 1) / B;
  const int gblk = (N + 63) / 64;
  const int g128 = (N + 127) / 128;
  const int nb1 = (N + SCAN_B - 1) / SCAN_B;  // 196

  // CSR build + norms (dinv fused into scan1)
  k_init<<<gN, B, 0, stream>>>(dinv, cnt, N);
  k_deg_cnt<<<gE, B, 0, stream>>>(dst, ew, dinv, cnt, E);
  k_scan1<<<nb1, SCAN_B, 0, stream>>>(cnt, rs, bsums, dinv, N);
  k_scan2<<<1, 256, 0, stream>>>(bsums, nb1);
  k_scan3<<<gN, B, 0, stream>>>(rs, bsums, cnt, N, E);
  k_fill<<<gE, B, 0, stream>>>(src, dst, ew, dinv, rs, cnt, ep, E);

  // layer 1 (bf16x3 MFMA GEMM)
  k_gemm1_mfma<<<g128, 256, 0, stream>>>(features, W1, H, N);
  k_gather64<<<(N * 64 + 255) / 256, 256, 0, stream>>>(H, ep, rs, dinv, AGG, N);

  // layer 2 (bias+relu of layer 1 fused into A-load)
  k_gemm_n64<<<gblk, 256, 0, stream>>>(AGG, W2, b1, H, N, 64);
  k_gather64<<<(N * 64 + 255) / 256, 256, 0, stream>>>(H, ep, rs, dinv, AGG, N);

  // layer 3 (bias+relu fused), 16-wide; H reused for the N x 16 result
  k_gemm_n16<<<gblk, 256, 0, stream>>>(AGG, W3, b2, H, N);
  k_gather16<<<(N * 16 + 255) / 256, 256, 0, stream>>>(H, ep, rs, dinv, b3, (float*)d_out, N);
}